// Round 9
// baseline (216.309 us; speedup 1.0000x reference)
//
#include <hip/hip_runtime.h>
#include <stdint.h>

#define B_ 4
#define T_ 1024
#define E_ 1024
#define H_ 16
#define HS_ 64
#define BT_ 4096

typedef unsigned short u16;
typedef __attribute__((ext_vector_type(8))) short bf16x8;
typedef __attribute__((ext_vector_type(4))) float f32x4;

__device__ __forceinline__ u16 f2bf(float f) {
    unsigned u = __float_as_uint(f);
    u += 0x7fff + ((u >> 16) & 1);   // round-to-nearest-even
    return (u16)(u >> 16);
}

__device__ __forceinline__ u16 f2bf_fast(float f) {
    // round-to-nearest (ties away); 2 VALU ops vs 4 for RNE
    return (u16)((__float_as_uint(f) + 0x8000u) >> 16);
}

__device__ __forceinline__ void gll16(const void* g, void* l) {
    __builtin_amdgcn_global_load_lds(
        (const __attribute__((address_space(1))) unsigned int*)g,
        (__attribute__((address_space(3))) unsigned int*)l, 16, 0, 0);
}

// ---------------------------------------------------------------------------
// LayerNorm for all three streams. One block (256 thr) per row of 1024.
// ---------------------------------------------------------------------------
__global__ __launch_bounds__(256) void ln_all(
    const float* __restrict__ v, const float* __restrict__ k,
    const float* __restrict__ q, const float* __restrict__ g,
    const float* __restrict__ b,
    u16* __restrict__ vn, u16* __restrict__ kn, u16* __restrict__ qn)
{
    int row = blockIdx.x;
    int which = row >> 12;
    int r = row & 4095;
    const float* src = which == 0 ? v : which == 1 ? k : q;
    u16* dst = which == 0 ? vn : which == 1 ? kn : qn;

    int t = threadIdx.x;
    float4 x = ((const float4*)(src + (size_t)r * E_))[t];
    float s  = x.x + x.y + x.z + x.w;
    float ss = x.x * x.x + x.y * x.y + x.z * x.z + x.w * x.w;
    for (int off = 32; off; off >>= 1) {
        s  += __shfl_down(s, off, 64);
        ss += __shfl_down(ss, off, 64);
    }
    __shared__ float red[8];
    int w = t >> 6, l = t & 63;
    if (l == 0) { red[w] = s; red[4 + w] = ss; }
    __syncthreads();
    float fs  = red[0] + red[1] + red[2] + red[3];
    float fss = red[4] + red[5] + red[6] + red[7];
    float mu  = fs * (1.0f / E_);
    float var = fss * (1.0f / E_) - mu * mu;
    float rstd = rsqrtf(var + 1e-5f);

    float4 gg = ((const float4*)g)[t];
    float4 bb = ((const float4*)b)[t];
    ushort4 o;
    o.x = f2bf((x.x - mu) * rstd * gg.x + bb.x);
    o.y = f2bf((x.y - mu) * rstd * gg.y + bb.y);
    o.z = f2bf((x.z - mu) * rstd * gg.z + bb.z);
    o.w = f2bf((x.w - mu) * rstd * gg.w + bb.w);
    ((ushort4*)(dst + (size_t)r * E_))[t] = o;
}

// ---------------------------------------------------------------------------
// Transpose + cast fp32 [K][N] -> bf16 [N][K]. 32x32 tiles.
// ---------------------------------------------------------------------------
__global__ __launch_bounds__(256) void wcast_t(
    const float* __restrict__ wq, const float* __restrict__ wk,
    const float* __restrict__ wv, const float* __restrict__ wp,
    u16* __restrict__ tq, u16* __restrict__ tk,
    u16* __restrict__ tv, u16* __restrict__ tp)
{
    int z = blockIdx.z;
    const float* src = z == 0 ? wq : z == 1 ? wk : z == 2 ? wv : wp;
    u16* dst = z == 0 ? tq : z == 1 ? tk : z == 2 ? tv : tp;
    __shared__ float tile[32][33];
    int n0 = blockIdx.x * 32, k0 = blockIdx.y * 32;
    int tx = threadIdx.x & 31, ty = threadIdx.x >> 5;   // 32 x 8
    for (int i = 0; i < 4; i++)
        tile[ty + i * 8][tx] = src[(size_t)(k0 + ty + i * 8) * E_ + n0 + tx];
    __syncthreads();
    for (int i = 0; i < 4; i++)
        dst[(size_t)(n0 + ty + i * 8) * E_ + k0 + tx] = f2bf(tile[tx][ty + i * 8]);
}

// ---------------------------------------------------------------------------
// GEMM C[128 x 128] tile (m97 structure) = X[128 x K] * Wt[128 x K]^T
// grid (8, 32, nz), 4 waves 2x2, wave subtile 64x64 (4x4 frags, 16 MFMA/step).
// Double-buffered BK=32; LDS swizzle chunk ^= (row>>1)&3; pre-swizzled global
// source keeps global_load_lds dest linear. XCD-chunked blockIdx swizzle.
// mode: 0=q scatter (prescaled by E^-0.5 * log2e for exp2 softmax),
//       1=k scatter, 2=v transposed, 3=f32+bias.
// ---------------------------------------------------------------------------
__global__ __launch_bounds__(256) void gemm128(
    const u16* __restrict__ X0, const u16* __restrict__ X1, const u16* __restrict__ X2,
    const u16* __restrict__ W0, const u16* __restrict__ W1, const u16* __restrict__ W2,
    u16* __restrict__ qh, u16* __restrict__ kh, u16* __restrict__ vt,
    float* __restrict__ outF, const float* __restrict__ bias, int fin)
{
    __shared__ __attribute__((aligned(16))) char smem[36864];
    // XCD swizzle: nwg = fin?256:768 (both %8==0), cpx = nwg/8
    int lid = blockIdx.x + 8 * (blockIdx.y + 32 * blockIdx.z);
    int cpx = fin ? 32 : 96;
    int swz = (lid & 7) * cpx + (lid >> 3);
    int bx = swz & 7;
    int by = (swz >> 3) & 31;
    int bz = swz >> 8;

    int mode = fin ? 3 : bz;
    const u16* X  = bz == 0 ? X0 : bz == 1 ? X1 : X2;
    const u16* Wt = bz == 0 ? W0 : bz == 1 ? W1 : W2;

    const int K = 1024;
    int n0 = bx * 128, m0 = by * 128;
    int t = threadIdx.x, w = t >> 6, l = t & 63;
    int lr = l & 15, lg = l >> 4, wm = w >> 1, wn = w & 1;

    f32x4 acc[4][4];
    f32x4 zero = {0.f, 0.f, 0.f, 0.f};
    for (int i = 0; i < 4; i++)
        for (int j = 0; j < 4; j++) acc[i][j] = zero;

    const char* Xb = (const char*)X + (size_t)m0 * 2048;
    const char* Wb = (const char*)Wt + (size_t)n0 * 2048;

    // staging: tile row = seg*16 + l>>2; source chunk pre-swizzled by
    // (row>>1)&3 == (l>>3)&3 (seg*8 = 0 mod 4)
    int scol = ((l & 3) ^ ((l >> 3) & 3)) * 16;

    auto stage = [&](int k0, int buf) {
        int kb = k0 * 2;
        for (int j = 0; j < 2; j++) {
            int seg = w * 2 + j;
            int row = seg * 16 + (l >> 2);
            gll16(Xb + (size_t)row * 2048 + kb + scol,
                  smem + buf * 8192 + seg * 1024 + l * 16);
            gll16(Wb + (size_t)row * 2048 + kb + scol,
                  smem + 16384 + buf * 8192 + seg * 1024 + l * 16);
        }
    };

    stage(0, 0);
    __syncthreads();
    int b = 0;
    int swr = (lr >> 1) & 3;                  // read-side swizzle key
    for (int k0 = 0; k0 < K; k0 += 32) {
        if (k0 + 32 < K) stage(k0 + 32, b ^ 1);
        const u16* As = (const u16*)(smem + b * 8192);
        const u16* Bs = (const u16*)(smem + 16384 + b * 8192);
        bf16x8 af[4], bfr[4];
        for (int i = 0; i < 4; i++)
            af[i] = *(const bf16x8*)&As[(wm * 64 + i * 16 + lr) * 32 + (lg ^ swr) * 8];
        for (int j = 0; j < 4; j++)
            bfr[j] = *(const bf16x8*)&Bs[(wn * 64 + j * 16 + lr) * 32 + (lg ^ swr) * 8];
        for (int i = 0; i < 4; i++)
            for (int j = 0; j < 4; j++)
                acc[i][j] = __builtin_amdgcn_mfma_f32_16x16x32_bf16(
                    af[i], bfr[j], acc[i][j], 0, 0, 0);
        __syncthreads();
        b ^= 1;
    }

    if (mode == 3) {
        for (int i = 0; i < 4; i++)
            for (int j = 0; j < 4; j++)
                for (int r = 0; r < 4; r++) {
                    int row = m0 + wm * 64 + i * 16 + lg * 4 + r;
                    int col = n0 + wn * 64 + j * 16 + lr;
                    outF[(size_t)row * E_ + col] = acc[i][j][r] + bias[col];
                }
    } else if (mode < 2) {
        u16* outB = mode == 0 ? qh : kh;
        // q: fold E^-0.5 AND log2(e) so attn uses exp2 directly
        float sc = mode == 0 ? 0.04508422f : 1.0f;
        for (int i = 0; i < 4; i++)
            for (int j = 0; j < 4; j++)
                for (int r = 0; r < 4; r++) {
                    int row = m0 + wm * 64 + i * 16 + lg * 4 + r;
                    int col = n0 + wn * 64 + j * 16 + lr;
                    int bb = row >> 10, tt = row & 1023;
                    int hh = col >> 6, dd = col & 63;
                    outB[(((size_t)(bb * H_ + hh)) * T_ + tt) * HS_ + dd] =
                        f2bf(acc[i][j][r] * sc);
                }
    } else {
        // V: transpose wave's 64(t) x 64(d) sub-tile through LDS -> [B,H,64,T]
        u16* Tt = (u16*)smem + w * 4608;           // [64 d][72] u16
        for (int i = 0; i < 4; i++)
            for (int j = 0; j < 4; j++)
                for (int r = 0; r < 4; r++)
                    Tt[(j * 16 + lr) * 72 + i * 16 + lg * 4 + r] = f2bf(acc[i][j][r]);
        int bb = m0 >> 10;
        int tbase = (m0 & 1023) + wm * 64;
        int hh = (n0 + wn * 64) >> 6;
        u16* outV = vt + ((size_t)(bb * H_ + hh)) * HS_ * T_;
        int dl = l >> 3, tc = l & 7;
        for (int u = 0; u < 8; u++) {
            int d = u * 8 + dl;
            bf16x8 vv = *(const bf16x8*)&Tt[d * 72 + tc * 8];
            *(bf16x8*)&outV[(size_t)d * T_ + tbase + tc * 8] = vv;
        }
    }
}

// ---------------------------------------------------------------------------
// Flash attention, causal. Block = 128 q-rows (wave owns 32), grid (8,64).
// Double-buffered K/V LDS staging (XOR-swizzled both sides), one barrier per
// 64-key tile, 32 MFMA/tile/wave. Softmax in exp2 units (log2e folded into
// Q): bare v_exp_f32, no v_mul. Defer-max (THR=11.5 log2 = 8 nat), cheap
// ties-away bf16 round for P, rcp-mul epilogue. XCD-chunked block swizzle.
// ---------------------------------------------------------------------------
__global__ __launch_bounds__(256) void attn(
    const u16* __restrict__ Qh, const u16* __restrict__ Kh,
    const u16* __restrict__ Vt, u16* __restrict__ Out)
{
    int lid = blockIdx.x + 8 * blockIdx.y;        // 512 blocks
    int swz = (lid & 7) * 64 + (lid >> 3);
    int qt = 7 - (swz & 7);                       // heavy tiles first
    int bh = swz >> 3;
    int b = bh >> 4, h = bh & 15;
    int t = threadIdx.x, w = t >> 6, l = t & 63;
    int lr = l & 15, lg = l >> 4;
    int sw = lr & 7;                              // read-side swizzle key

    __shared__ __attribute__((aligned(16))) u16 Ks[2][4096];
    __shared__ __attribute__((aligned(16))) u16 Vs[2][4096];
    __shared__ __attribute__((aligned(16))) u16 Ps[4][2048];

    const char* Kb = (const char*)(Kh + (size_t)bh * T_ * HS_);
    const char* Vb = (const char*)(Vt + (size_t)bh * HS_ * T_);
    const u16*  Qb = Qh + (size_t)bh * T_ * HS_;

    int ris = l >> 3;                  // staging row within 8-row segment
    int csw = (l & 7) ^ ris;           // pre-swizzled source chunk

    bf16x8 qf[2][2];
    for (int i = 0; i < 2; i++) {
        int qrow = qt * 128 + w * 32 + i * 16 + lr;
        qf[i][0] = *(const bf16x8*)&Qb[qrow * 64 + lg * 8];
        qf[i][1] = *(const bf16x8*)&Qb[qrow * 64 + 32 + lg * 8];
    }

    f32x4 zero = {0.f, 0.f, 0.f, 0.f};
    f32x4 o[2][4];
    float m[2][4], psum[2][4];
    for (int i = 0; i < 2; i++)
        for (int nf = 0; nf < 4; nf++) o[i][nf] = zero;
    for (int i = 0; i < 2; i++)
        for (int r = 0; r < 4; r++) { m[i][r] = -1e30f; psum[i][r] = 0.f; }

    int nkv = 2 * qt + 2;

    auto stageKV = [&](int kt2, int bsel) {
        int kv0 = kt2 * 64;
        for (int j = 0; j < 2; j++) {
            int seg = w * 2 + j;
            int row = seg * 8 + ris;
            gll16(Kb + (size_t)(kv0 + row) * 128 + csw * 16,
                  (char*)Ks[bsel] + seg * 1024);
            gll16(Vb + (size_t)row * 2048 + (size_t)kv0 * 2 + csw * 16,
                  (char*)Vs[bsel] + seg * 1024);
        }
    };

    stageKV(0, 0);
    __syncthreads();
    int bsel = 0;

    for (int kt = 0; kt < nkv; kt++) {
        if (kt + 1 < nkv) stageKV(kt + 1, bsel ^ 1);

        int kv0 = kt * 64;
        const u16* Kl = Ks[bsel];
        const u16* Vl = Vs[bsel];

        // S = Q K^T : 16 MFMA (scores in log2 units; log2e folded into Q)
        f32x4 s[2][4];
        __builtin_amdgcn_s_setprio(1);
        for (int kf = 0; kf < 4; kf++) {
            int key = kf * 16 + lr;
            bf16x8 bk0 = *(const bf16x8*)&Kl[key * 64 + (lg ^ sw) * 8];
            bf16x8 bk1 = *(const bf16x8*)&Kl[key * 64 + ((lg + 4) ^ sw) * 8];
            for (int i = 0; i < 2; i++) {
                s[i][kf] = __builtin_amdgcn_mfma_f32_16x16x32_bf16(qf[i][0], bk0, zero, 0, 0, 0);
                s[i][kf] = __builtin_amdgcn_mfma_f32_16x16x32_bf16(qf[i][1], bk1, s[i][kf], 0, 0, 0);
            }
        }
        __builtin_amdgcn_s_setprio(0);

        if (kt >= 2 * qt) {            // last two tiles touch the diagonal
            for (int i = 0; i < 2; i++)
                for (int kf = 0; kf < 4; kf++)
                    for (int r = 0; r < 4; r++) {
                        int key = kv0 + kf * 16 + lr;
                        int qr  = qt * 128 + w * 32 + i * 16 + lg * 4 + r;
                        if (key > qr) s[i][kf][r] = -1e30f;
                    }
        }

        // defer-max: per-lane max + wave vote (rarely rescales)
        float pmr[2][4];
        bool ok = true;
        for (int i = 0; i < 2; i++)
            for (int r = 0; r < 4; r++) {
                pmr[i][r] = fmaxf(fmaxf(s[i][0][r], s[i][1][r]),
                                  fmaxf(s[i][2][r], s[i][3][r]));
                ok &= (pmr[i][r] <= m[i][r] + 11.5f);
            }
        if (!__all(ok)) {
            for (int i = 0; i < 2; i++)
                for (int r = 0; r < 4; r++) {
                    float mt = pmr[i][r];
                    for (int off = 1; off < 16; off <<= 1)
                        mt = fmaxf(mt, __shfl_xor(mt, off, 64));
                    float mn = fmaxf(m[i][r], mt);
                    float al = exp2f(m[i][r] - mn);
                    m[i][r] = mn;
                    psum[i][r] *= al;
                    for (int nf = 0; nf < 4; nf++) o[i][nf][r] *= al;
                }
        }

        // exp2 + per-lane partial sum + P -> per-wave LDS (swizzled)
        for (int i = 0; i < 2; i++)
            for (int kf = 0; kf < 4; kf++)
                for (int r = 0; r < 4; r++) {
                    float p = exp2f(s[i][kf][r] - m[i][r]);
                    psum[i][r] += p;
                    int row = i * 16 + lg * 4 + r;
                    int ch  = (kf * 2 + (lr >> 3)) ^ (row & 7);
                    Ps[w][row * 64 + ch * 8 + sw] = f2bf_fast(p);
                }

        // O += P V : 16 MFMA; V-frags shared across both q-frag-groups
        __builtin_amdgcn_s_setprio(1);
        for (int ks = 0; ks < 2; ks++) {
            bf16x8 pa0 = *(const bf16x8*)&Ps[w][(lr) * 64 + ((ks * 4 + lg) ^ sw) * 8];
            bf16x8 pa1 = *(const bf16x8*)&Ps[w][(16 + lr) * 64 + ((ks * 4 + lg) ^ sw) * 8];
            for (int nf = 0; nf < 4; nf++) {
                int d = nf * 16 + lr;
                bf16x8 bv = *(const bf16x8*)&Vl[d * 64 + ((ks * 4 + lg) ^ sw) * 8];
                o[0][nf] = __builtin_amdgcn_mfma_f32_16x16x32_bf16(pa0, bv, o[0][nf], 0, 0, 0);
                o[1][nf] = __builtin_amdgcn_mfma_f32_16x16x32_bf16(pa1, bv, o[1][nf], 0, 0, 0);
            }
        }
        __builtin_amdgcn_s_setprio(0);
        __syncthreads();
        bsel ^= 1;
    }

    // final sum reduce (once per block) + reciprocal
    for (int i = 0; i < 2; i++)
        for (int r = 0; r < 4; r++) {
            for (int off = 1; off < 16; off <<= 1)
                psum[i][r] += __shfl_xor(psum[i][r], off, 64);
            psum[i][r] = __frcp_rn(psum[i][r]);
        }

    for (int i = 0; i < 2; i++)
        for (int nf = 0; nf < 4; nf++)
            for (int r = 0; r < 4; r++) {
                int row = qt * 128 + w * 32 + i * 16 + lg * 4 + r;
                int col = h * 64 + nf * 16 + lr;
                Out[((size_t)(b * T_ + row)) * E_ + col] = f2bf(o[i][nf][r] * psum[i][r]);
            }
}

// ---------------------------------------------------------------------------
extern "C" void kernel_launch(void* const* d_in, const int* in_sizes, int n_in,
                              void* d_out, int out_size, void* d_ws, size_t ws_size,
                              hipStream_t stream) {
    const float* v  = (const float*)d_in[0];
    const float* k  = (const float*)d_in[1];
    const float* q  = (const float*)d_in[2];
    const float* g  = (const float*)d_in[3];
    const float* be = (const float*)d_in[4];
    const float* Wq = (const float*)d_in[5];
    const float* Wk = (const float*)d_in[6];
    const float* Wv = (const float*)d_in[7];
    const float* Wp = (const float*)d_in[8];
    const float* bp = (const float*)d_in[9];
    float* out = (float*)d_out;

    char* ws = (char*)d_ws;
    u16* qh  = (u16*)(ws);                // 8MB [B,H,T,64]  (pre-scaled)
    u16* kh  = (u16*)(ws + (8u  << 20));  // 8MB [B,H,T,64]
    u16* vt  = (u16*)(ws + (16u << 20));  // 8MB [B,H,64,T]
    u16* qn  = (u16*)(ws + (24u << 20));  // 8MB [B,T,E]
    u16* kn  = (u16*)(ws + (32u << 20));  // 8MB
    u16* vn  = (u16*)(ws + (40u << 20));  // 8MB
    u16* wtq = (u16*)(ws + (48u << 20));  // 2MB each
    u16* wtk = (u16*)(ws + (50u << 20));
    u16* wtv = (u16*)(ws + (52u << 20));
    u16* wtp = (u16*)(ws + (54u << 20));
    u16* ao  = (u16*)(ws + (24u << 20));  // alias qn (dead after projections)

    hipLaunchKernelGGL(wcast_t, dim3(32, 32, 4), dim3(256), 0, stream,
                       Wq, Wk, Wv, Wp, wtq, wtk, wtv, wtp);
    hipLaunchKernelGGL(ln_all, dim3(3 * BT_), dim3(256), 0, stream,
                       v, k, q, g, be, vn, kn, qn);
    hipLaunchKernelGGL(gemm128, dim3(8, 32, 3), dim3(256), 0, stream,
                       qn, kn, vn, wtq, wtk, wtv, qh, kh, vt,
                       (float*)nullptr, (const float*)nullptr, 0);
    hipLaunchKernelGGL(attn, dim3(8, 64), dim3(256), 0, stream,
                       qh, kh, vt, ao);
    hipLaunchKernelGGL(gemm128, dim3(8, 32, 1), dim3(256), 0, stream,
                       ao, ao, ao, wtp, wtp, wtp,
                       (u16*)nullptr, (u16*)nullptr, (u16*)nullptr, out, bp, 1);
}

// Round 10
// 207.746 us; speedup vs baseline: 1.0412x; 1.0412x over previous
//
#include <hip/hip_runtime.h>
#include <stdint.h>

#define B_ 4
#define T_ 1024
#define E_ 1024
#define H_ 16
#define HS_ 64
#define BT_ 4096

typedef unsigned short u16;
typedef __attribute__((ext_vector_type(8))) short bf16x8;
typedef __attribute__((ext_vector_type(4))) float f32x4;

__device__ __forceinline__ u16 f2bf(float f) {
    unsigned u = __float_as_uint(f);
    u += 0x7fff + ((u >> 16) & 1);   // round-to-nearest-even
    return (u16)(u >> 16);
}

__device__ __forceinline__ u16 f2bf_fast(float f) {
    // round-to-nearest (ties away); 2 VALU ops vs 4 for RNE
    return (u16)((__float_as_uint(f) + 0x8000u) >> 16);
}

// NATIVE hw exp2 (single v_exp_f32). exp2f() is the OCML libm routine with a
// denormal fixup branch -- measured +13us regression in r9. Do not use it.
__device__ __forceinline__ float fexp2(float x) {
#if __has_builtin(__builtin_amdgcn_exp2f)
    return __builtin_amdgcn_exp2f(x);
#else
    float r; asm("v_exp_f32 %0, %1" : "=v"(r) : "v"(x)); return r;
#endif
}

__device__ __forceinline__ float frcp(float x) {
#if __has_builtin(__builtin_amdgcn_rcpf)
    return __builtin_amdgcn_rcpf(x);
#else
    float r; asm("v_rcp_f32 %0, %1" : "=v"(r) : "v"(x)); return r;
#endif
}

__device__ __forceinline__ void gll16(const void* g, void* l) {
    __builtin_amdgcn_global_load_lds(
        (const __attribute__((address_space(1))) unsigned int*)g,
        (__attribute__((address_space(3))) unsigned int*)l, 16, 0, 0);
}

// ---------------------------------------------------------------------------
// LayerNorm for all three streams. One block (256 thr) per row of 1024.
// ---------------------------------------------------------------------------
__global__ __launch_bounds__(256) void ln_all(
    const float* __restrict__ v, const float* __restrict__ k,
    const float* __restrict__ q, const float* __restrict__ g,
    const float* __restrict__ b,
    u16* __restrict__ vn, u16* __restrict__ kn, u16* __restrict__ qn)
{
    int row = blockIdx.x;
    int which = row >> 12;
    int r = row & 4095;
    const float* src = which == 0 ? v : which == 1 ? k : q;
    u16* dst = which == 0 ? vn : which == 1 ? kn : qn;

    int t = threadIdx.x;
    float4 x = ((const float4*)(src + (size_t)r * E_))[t];
    float s  = x.x + x.y + x.z + x.w;
    float ss = x.x * x.x + x.y * x.y + x.z * x.z + x.w * x.w;
    for (int off = 32; off; off >>= 1) {
        s  += __shfl_down(s, off, 64);
        ss += __shfl_down(ss, off, 64);
    }
    __shared__ float red[8];
    int w = t >> 6, l = t & 63;
    if (l == 0) { red[w] = s; red[4 + w] = ss; }
    __syncthreads();
    float fs  = red[0] + red[1] + red[2] + red[3];
    float fss = red[4] + red[5] + red[6] + red[7];
    float mu  = fs * (1.0f / E_);
    float var = fss * (1.0f / E_) - mu * mu;
    float rstd = rsqrtf(var + 1e-5f);

    float4 gg = ((const float4*)g)[t];
    float4 bb = ((const float4*)b)[t];
    ushort4 o;
    o.x = f2bf((x.x - mu) * rstd * gg.x + bb.x);
    o.y = f2bf((x.y - mu) * rstd * gg.y + bb.y);
    o.z = f2bf((x.z - mu) * rstd * gg.z + bb.z);
    o.w = f2bf((x.w - mu) * rstd * gg.w + bb.w);
    ((ushort4*)(dst + (size_t)r * E_))[t] = o;
}

// ---------------------------------------------------------------------------
// Transpose + cast fp32 [K][N] -> bf16 [N][K]. 32x32 tiles.
// ---------------------------------------------------------------------------
__global__ __launch_bounds__(256) void wcast_t(
    const float* __restrict__ wq, const float* __restrict__ wk,
    const float* __restrict__ wv, const float* __restrict__ wp,
    u16* __restrict__ tq, u16* __restrict__ tk,
    u16* __restrict__ tv, u16* __restrict__ tp)
{
    int z = blockIdx.z;
    const float* src = z == 0 ? wq : z == 1 ? wk : z == 2 ? wv : wp;
    u16* dst = z == 0 ? tq : z == 1 ? tk : z == 2 ? tv : tp;
    __shared__ float tile[32][33];
    int n0 = blockIdx.x * 32, k0 = blockIdx.y * 32;
    int tx = threadIdx.x & 31, ty = threadIdx.x >> 5;   // 32 x 8
    for (int i = 0; i < 4; i++)
        tile[ty + i * 8][tx] = src[(size_t)(k0 + ty + i * 8) * E_ + n0 + tx];
    __syncthreads();
    for (int i = 0; i < 4; i++)
        dst[(size_t)(n0 + ty + i * 8) * E_ + k0 + tx] = f2bf(tile[tx][ty + i * 8]);
}

// ---------------------------------------------------------------------------
// GEMM C[128 x 128] tile (m97 structure) = X[128 x K] * Wt[128 x K]^T
// grid (8, 32, nz), 4 waves 2x2, wave subtile 64x64 (4x4 frags, 16 MFMA/step).
// Double-buffered BK=32; LDS swizzle chunk ^= (row>>1)&3; pre-swizzled global
// source keeps global_load_lds dest linear. XCD-chunked blockIdx swizzle.
// mode: 0=q scatter (prescaled by E^-0.5 * log2e for exp2 softmax),
//       1=k scatter, 2=v transposed, 3=f32+bias.
// ---------------------------------------------------------------------------
__global__ __launch_bounds__(256) void gemm128(
    const u16* __restrict__ X0, const u16* __restrict__ X1, const u16* __restrict__ X2,
    const u16* __restrict__ W0, const u16* __restrict__ W1, const u16* __restrict__ W2,
    u16* __restrict__ qh, u16* __restrict__ kh, u16* __restrict__ vt,
    float* __restrict__ outF, const float* __restrict__ bias, int fin)
{
    __shared__ __attribute__((aligned(16))) char smem[36864];
    // XCD swizzle: nwg = fin?256:768 (both %8==0), cpx = nwg/8
    int lid = blockIdx.x + 8 * (blockIdx.y + 32 * blockIdx.z);
    int cpx = fin ? 32 : 96;
    int swz = (lid & 7) * cpx + (lid >> 3);
    int bx = swz & 7;
    int by = (swz >> 3) & 31;
    int bz = swz >> 8;

    int mode = fin ? 3 : bz;
    const u16* X  = bz == 0 ? X0 : bz == 1 ? X1 : X2;
    const u16* Wt = bz == 0 ? W0 : bz == 1 ? W1 : W2;

    const int K = 1024;
    int n0 = bx * 128, m0 = by * 128;
    int t = threadIdx.x, w = t >> 6, l = t & 63;
    int lr = l & 15, lg = l >> 4, wm = w >> 1, wn = w & 1;

    f32x4 acc[4][4];
    f32x4 zero = {0.f, 0.f, 0.f, 0.f};
    for (int i = 0; i < 4; i++)
        for (int j = 0; j < 4; j++) acc[i][j] = zero;

    const char* Xb = (const char*)X + (size_t)m0 * 2048;
    const char* Wb = (const char*)Wt + (size_t)n0 * 2048;

    // staging: tile row = seg*16 + l>>2; source chunk pre-swizzled by
    // (row>>1)&3 == (l>>3)&3 (seg*8 = 0 mod 4)
    int scol = ((l & 3) ^ ((l >> 3) & 3)) * 16;

    auto stage = [&](int k0, int buf) {
        int kb = k0 * 2;
        for (int j = 0; j < 2; j++) {
            int seg = w * 2 + j;
            int row = seg * 16 + (l >> 2);
            gll16(Xb + (size_t)row * 2048 + kb + scol,
                  smem + buf * 8192 + seg * 1024 + l * 16);
            gll16(Wb + (size_t)row * 2048 + kb + scol,
                  smem + 16384 + buf * 8192 + seg * 1024 + l * 16);
        }
    };

    stage(0, 0);
    __syncthreads();
    int b = 0;
    int swr = (lr >> 1) & 3;                  // read-side swizzle key
    for (int k0 = 0; k0 < K; k0 += 32) {
        if (k0 + 32 < K) stage(k0 + 32, b ^ 1);
        const u16* As = (const u16*)(smem + b * 8192);
        const u16* Bs = (const u16*)(smem + 16384 + b * 8192);
        bf16x8 af[4], bfr[4];
        for (int i = 0; i < 4; i++)
            af[i] = *(const bf16x8*)&As[(wm * 64 + i * 16 + lr) * 32 + (lg ^ swr) * 8];
        for (int j = 0; j < 4; j++)
            bfr[j] = *(const bf16x8*)&Bs[(wn * 64 + j * 16 + lr) * 32 + (lg ^ swr) * 8];
        for (int i = 0; i < 4; i++)
            for (int j = 0; j < 4; j++)
                acc[i][j] = __builtin_amdgcn_mfma_f32_16x16x32_bf16(
                    af[i], bfr[j], acc[i][j], 0, 0, 0);
        __syncthreads();
        b ^= 1;
    }

    if (mode == 3) {
        for (int i = 0; i < 4; i++)
            for (int j = 0; j < 4; j++)
                for (int r = 0; r < 4; r++) {
                    int row = m0 + wm * 64 + i * 16 + lg * 4 + r;
                    int col = n0 + wn * 64 + j * 16 + lr;
                    outF[(size_t)row * E_ + col] = acc[i][j][r] + bias[col];
                }
    } else if (mode < 2) {
        u16* outB = mode == 0 ? qh : kh;
        // q: fold E^-0.5 AND log2(e) so attn uses exp2 directly
        float sc = mode == 0 ? 0.04508422f : 1.0f;
        for (int i = 0; i < 4; i++)
            for (int j = 0; j < 4; j++)
                for (int r = 0; r < 4; r++) {
                    int row = m0 + wm * 64 + i * 16 + lg * 4 + r;
                    int col = n0 + wn * 64 + j * 16 + lr;
                    int bb = row >> 10, tt = row & 1023;
                    int hh = col >> 6, dd = col & 63;
                    outB[(((size_t)(bb * H_ + hh)) * T_ + tt) * HS_ + dd] =
                        f2bf(acc[i][j][r] * sc);
                }
    } else {
        // V: transpose wave's 64(t) x 64(d) sub-tile through LDS -> [B,H,64,T]
        u16* Tt = (u16*)smem + w * 4608;           // [64 d][72] u16
        for (int i = 0; i < 4; i++)
            for (int j = 0; j < 4; j++)
                for (int r = 0; r < 4; r++)
                    Tt[(j * 16 + lr) * 72 + i * 16 + lg * 4 + r] = f2bf(acc[i][j][r]);
        int bb = m0 >> 10;
        int tbase = (m0 & 1023) + wm * 64;
        int hh = (n0 + wn * 64) >> 6;
        u16* outV = vt + ((size_t)(bb * H_ + hh)) * HS_ * T_;
        int dl = l >> 3, tc = l & 7;
        for (int u = 0; u < 8; u++) {
            int d = u * 8 + dl;
            bf16x8 vv = *(const bf16x8*)&Tt[d * 72 + tc * 8];
            *(bf16x8*)&outV[(size_t)d * T_ + tbase + tc * 8] = vv;
        }
    }
}

// ---------------------------------------------------------------------------
// Flash attention, causal. Block = 128 q-rows (wave owns 32), grid (8,64).
// Double-buffered K/V LDS staging (XOR-swizzled both sides), one barrier per
// 64-key tile, 32 MFMA/tile/wave. Softmax in exp2 units (log2e folded into
// Q): NATIVE v_exp_f32 only. Defer-max (THR=11.5 log2 = 8 nat), cheap
// ties-away bf16 round for P, rcp-mul epilogue. XCD-chunked block swizzle.
// ---------------------------------------------------------------------------
__global__ __launch_bounds__(256) void attn(
    const u16* __restrict__ Qh, const u16* __restrict__ Kh,
    const u16* __restrict__ Vt, u16* __restrict__ Out)
{
    int lid = blockIdx.x + 8 * blockIdx.y;        // 512 blocks
    int swz = (lid & 7) * 64 + (lid >> 3);
    int qt = 7 - (swz & 7);                       // heavy tiles first
    int bh = swz >> 3;
    int b = bh >> 4, h = bh & 15;
    int t = threadIdx.x, w = t >> 6, l = t & 63;
    int lr = l & 15, lg = l >> 4;
    int sw = lr & 7;                              // read-side swizzle key

    __shared__ __attribute__((aligned(16))) u16 Ks[2][4096];
    __shared__ __attribute__((aligned(16))) u16 Vs[2][4096];
    __shared__ __attribute__((aligned(16))) u16 Ps[4][2048];

    const char* Kb = (const char*)(Kh + (size_t)bh * T_ * HS_);
    const char* Vb = (const char*)(Vt + (size_t)bh * HS_ * T_);
    const u16*  Qb = Qh + (size_t)bh * T_ * HS_;

    int ris = l >> 3;                  // staging row within 8-row segment
    int csw = (l & 7) ^ ris;           // pre-swizzled source chunk

    bf16x8 qf[2][2];
    for (int i = 0; i < 2; i++) {
        int qrow = qt * 128 + w * 32 + i * 16 + lr;
        qf[i][0] = *(const bf16x8*)&Qb[qrow * 64 + lg * 8];
        qf[i][1] = *(const bf16x8*)&Qb[qrow * 64 + 32 + lg * 8];
    }

    f32x4 zero = {0.f, 0.f, 0.f, 0.f};
    f32x4 o[2][4];
    float m[2][4], psum[2][4];
    for (int i = 0; i < 2; i++)
        for (int nf = 0; nf < 4; nf++) o[i][nf] = zero;
    for (int i = 0; i < 2; i++)
        for (int r = 0; r < 4; r++) { m[i][r] = -1e30f; psum[i][r] = 0.f; }

    int nkv = 2 * qt + 2;

    auto stageKV = [&](int kt2, int bsel) {
        int kv0 = kt2 * 64;
        for (int j = 0; j < 2; j++) {
            int seg = w * 2 + j;
            int row = seg * 8 + ris;
            gll16(Kb + (size_t)(kv0 + row) * 128 + csw * 16,
                  (char*)Ks[bsel] + seg * 1024);
            gll16(Vb + (size_t)row * 2048 + (size_t)kv0 * 2 + csw * 16,
                  (char*)Vs[bsel] + seg * 1024);
        }
    };

    stageKV(0, 0);
    __syncthreads();
    int bsel = 0;

    for (int kt = 0; kt < nkv; kt++) {
        if (kt + 1 < nkv) stageKV(kt + 1, bsel ^ 1);

        int kv0 = kt * 64;
        const u16* Kl = Ks[bsel];
        const u16* Vl = Vs[bsel];

        // S = Q K^T : 16 MFMA (scores in log2 units; log2e folded into Q)
        f32x4 s[2][4];
        __builtin_amdgcn_s_setprio(1);
        for (int kf = 0; kf < 4; kf++) {
            int key = kf * 16 + lr;
            bf16x8 bk0 = *(const bf16x8*)&Kl[key * 64 + (lg ^ sw) * 8];
            bf16x8 bk1 = *(const bf16x8*)&Kl[key * 64 + ((lg + 4) ^ sw) * 8];
            for (int i = 0; i < 2; i++) {
                s[i][kf] = __builtin_amdgcn_mfma_f32_16x16x32_bf16(qf[i][0], bk0, zero, 0, 0, 0);
                s[i][kf] = __builtin_amdgcn_mfma_f32_16x16x32_bf16(qf[i][1], bk1, s[i][kf], 0, 0, 0);
            }
        }
        __builtin_amdgcn_s_setprio(0);

        if (kt >= 2 * qt) {            // last two tiles touch the diagonal
            for (int i = 0; i < 2; i++)
                for (int kf = 0; kf < 4; kf++)
                    for (int r = 0; r < 4; r++) {
                        int key = kv0 + kf * 16 + lr;
                        int qr  = qt * 128 + w * 32 + i * 16 + lg * 4 + r;
                        if (key > qr) s[i][kf][r] = -1e30f;
                    }
        }

        // defer-max: per-lane max + wave vote (rarely rescales)
        float pmr[2][4];
        bool ok = true;
        for (int i = 0; i < 2; i++)
            for (int r = 0; r < 4; r++) {
                pmr[i][r] = fmaxf(fmaxf(s[i][0][r], s[i][1][r]),
                                  fmaxf(s[i][2][r], s[i][3][r]));
                ok &= (pmr[i][r] <= m[i][r] + 11.5f);
            }
        if (!__all(ok)) {
            for (int i = 0; i < 2; i++)
                for (int r = 0; r < 4; r++) {
                    float mt = pmr[i][r];
                    for (int off = 1; off < 16; off <<= 1)
                        mt = fmaxf(mt, __shfl_xor(mt, off, 64));
                    float mn = fmaxf(m[i][r], mt);
                    float al = fexp2(m[i][r] - mn);
                    m[i][r] = mn;
                    psum[i][r] *= al;
                    for (int nf = 0; nf < 4; nf++) o[i][nf][r] *= al;
                }
        }

        // native exp2 + per-lane partial sum + P -> per-wave LDS (swizzled)
        for (int i = 0; i < 2; i++)
            for (int kf = 0; kf < 4; kf++)
                for (int r = 0; r < 4; r++) {
                    float p = fexp2(s[i][kf][r] - m[i][r]);
                    psum[i][r] += p;
                    int row = i * 16 + lg * 4 + r;
                    int ch  = (kf * 2 + (lr >> 3)) ^ (row & 7);
                    Ps[w][row * 64 + ch * 8 + sw] = f2bf_fast(p);
                }

        // O += P V : 16 MFMA; V-frags shared across both q-frag-groups
        __builtin_amdgcn_s_setprio(1);
        for (int ks = 0; ks < 2; ks++) {
            bf16x8 pa0 = *(const bf16x8*)&Ps[w][(lr) * 64 + ((ks * 4 + lg) ^ sw) * 8];
            bf16x8 pa1 = *(const bf16x8*)&Ps[w][(16 + lr) * 64 + ((ks * 4 + lg) ^ sw) * 8];
            for (int nf = 0; nf < 4; nf++) {
                int d = nf * 16 + lr;
                bf16x8 bv = *(const bf16x8*)&Vl[d * 64 + ((ks * 4 + lg) ^ sw) * 8];
                o[0][nf] = __builtin_amdgcn_mfma_f32_16x16x32_bf16(pa0, bv, o[0][nf], 0, 0, 0);
                o[1][nf] = __builtin_amdgcn_mfma_f32_16x16x32_bf16(pa1, bv, o[1][nf], 0, 0, 0);
            }
        }
        __builtin_amdgcn_s_setprio(0);
        __syncthreads();
        bsel ^= 1;
    }

    // final sum reduce (once per block) + native reciprocal
    for (int i = 0; i < 2; i++)
        for (int r = 0; r < 4; r++) {
            for (int off = 1; off < 16; off <<= 1)
                psum[i][r] += __shfl_xor(psum[i][r], off, 64);
            psum[i][r] = frcp(psum[i][r]);
        }

    for (int i = 0; i < 2; i++)
        for (int nf = 0; nf < 4; nf++)
            for (int r = 0; r < 4; r++) {
                int row = qt * 128 + w * 32 + i * 16 + lg * 4 + r;
                int col = h * 64 + nf * 16 + lr;
                Out[((size_t)(b * T_ + row)) * E_ + col] = f2bf(o[i][nf][r] * psum[i][r]);
            }
}

// ---------------------------------------------------------------------------
extern "C" void kernel_launch(void* const* d_in, const int* in_sizes, int n_in,
                              void* d_out, int out_size, void* d_ws, size_t ws_size,
                              hipStream_t stream) {
    const float* v  = (const float*)d_in[0];
    const float* k  = (const float*)d_in[1];
    const float* q  = (const float*)d_in[2];
    const float* g  = (const float*)d_in[3];
    const float* be = (const float*)d_in[4];
    const float* Wq = (const float*)d_in[5];
    const float* Wk = (const float*)d_in[6];
    const float* Wv = (const float*)d_in[7];
    const float* Wp = (const float*)d_in[8];
    const float* bp = (const float*)d_in[9];
    float* out = (float*)d_out;

    char* ws = (char*)d_ws;
    u16* qh  = (u16*)(ws);                // 8MB [B,H,T,64]  (pre-scaled)
    u16* kh  = (u16*)(ws + (8u  << 20));  // 8MB [B,H,T,64]
    u16* vt  = (u16*)(ws + (16u << 20));  // 8MB [B,H,64,T]
    u16* qn  = (u16*)(ws + (24u << 20));  // 8MB [B,T,E]
    u16* kn  = (u16*)(ws + (32u << 20));  // 8MB
    u16* vn  = (u16*)(ws + (40u << 20));  // 8MB
    u16* wtq = (u16*)(ws + (48u << 20));  // 2MB each
    u16* wtk = (u16*)(ws + (50u << 20));
    u16* wtv = (u16*)(ws + (52u << 20));
    u16* wtp = (u16*)(ws + (54u << 20));
    u16* ao  = (u16*)(ws + (24u << 20));  // alias qn (dead after projections)

    hipLaunchKernelGGL(wcast_t, dim3(32, 32, 4), dim3(256), 0, stream,
                       Wq, Wk, Wv, Wp, wtq, wtk, wtv, wtp);
    hipLaunchKernelGGL(ln_all, dim3(3 * BT_), dim3(256), 0, stream,
                       v, k, q, g, be, vn, kn, qn);
    hipLaunchKernelGGL(gemm128, dim3(8, 32, 3), dim3(256), 0, stream,
                       qn, kn, vn, wtq, wtk, wtv, qh, kh, vt,
                       (float*)nullptr, (const float*)nullptr, 0);
    hipLaunchKernelGGL(attn, dim3(8, 64), dim3(256), 0, stream,
                       qh, kh, vt, ao);
    hipLaunchKernelGGL(gemm128, dim3(8, 32, 1), dim3(256), 0, stream,
                       ao, ao, ao, wtp, wtp, wtp,
                       (u16*)nullptr, (u16*)nullptr, (u16*)nullptr, out, bp, 1);
}

// Round 12
// 202.764 us; speedup vs baseline: 1.0668x; 1.0246x over previous
//
#include <hip/hip_runtime.h>
#include <stdint.h>

#define B_ 4
#define T_ 1024
#define E_ 1024
#define H_ 16
#define HS_ 64
#define BT_ 4096

typedef unsigned short u16;
typedef __attribute__((ext_vector_type(8))) short bf16x8;
typedef __attribute__((ext_vector_type(4))) float f32x4;

__device__ __forceinline__ u16 f2bf(float f) {
    unsigned u = __float_as_uint(f);
    u += 0x7fff + ((u >> 16) & 1);   // round-to-nearest-even
    return (u16)(u >> 16);
}

__device__ __forceinline__ u16 f2bf_fast(float f) {
    // round-to-nearest (ties away); 2 VALU ops vs 4 for RNE
    return (u16)((__float_as_uint(f) + 0x8000u) >> 16);
}

// NATIVE hw exp2 (single v_exp_f32). exp2f() is the OCML libm routine with a
// denormal fixup branch -- measured +13us regression in r9. Do not use it.
__device__ __forceinline__ float fexp2(float x) {
#if __has_builtin(__builtin_amdgcn_exp2f)
    return __builtin_amdgcn_exp2f(x);
#else
    float r; asm("v_exp_f32 %0, %1" : "=v"(r) : "v"(x)); return r;
#endif
}

__device__ __forceinline__ float frcp(float x) {
#if __has_builtin(__builtin_amdgcn_rcpf)
    return __builtin_amdgcn_rcpf(x);
#else
    float r; asm("v_rcp_f32 %0, %1" : "=v"(r) : "v"(x)); return r;
#endif
}

__device__ __forceinline__ void gll16(const void* g, void* l) {
    __builtin_amdgcn_global_load_lds(
        (const __attribute__((address_space(1))) unsigned int*)g,
        (__attribute__((address_space(3))) unsigned int*)l, 16, 0, 0);
}

// ---------------------------------------------------------------------------
// LayerNorm for all three streams. One block (256 thr) per row of 1024.
// ---------------------------------------------------------------------------
__global__ __launch_bounds__(256) void ln_all(
    const float* __restrict__ v, const float* __restrict__ k,
    const float* __restrict__ q, const float* __restrict__ g,
    const float* __restrict__ b,
    u16* __restrict__ vn, u16* __restrict__ kn, u16* __restrict__ qn)
{
    int row = blockIdx.x;
    int which = row >> 12;
    int r = row & 4095;
    const float* src = which == 0 ? v : which == 1 ? k : q;
    u16* dst = which == 0 ? vn : which == 1 ? kn : qn;

    int t = threadIdx.x;
    float4 x = ((const float4*)(src + (size_t)r * E_))[t];
    float s  = x.x + x.y + x.z + x.w;
    float ss = x.x * x.x + x.y * x.y + x.z * x.z + x.w * x.w;
    for (int off = 32; off; off >>= 1) {
        s  += __shfl_down(s, off, 64);
        ss += __shfl_down(ss, off, 64);
    }
    __shared__ float red[8];
    int w = t >> 6, l = t & 63;
    if (l == 0) { red[w] = s; red[4 + w] = ss; }
    __syncthreads();
    float fs  = red[0] + red[1] + red[2] + red[3];
    float fss = red[4] + red[5] + red[6] + red[7];
    float mu  = fs * (1.0f / E_);
    float var = fss * (1.0f / E_) - mu * mu;
    float rstd = rsqrtf(var + 1e-5f);

    float4 gg = ((const float4*)g)[t];
    float4 bb = ((const float4*)b)[t];
    ushort4 o;
    o.x = f2bf((x.x - mu) * rstd * gg.x + bb.x);
    o.y = f2bf((x.y - mu) * rstd * gg.y + bb.y);
    o.z = f2bf((x.z - mu) * rstd * gg.z + bb.z);
    o.w = f2bf((x.w - mu) * rstd * gg.w + bb.w);
    ((ushort4*)(dst + (size_t)r * E_))[t] = o;
}

// ---------------------------------------------------------------------------
// Transpose + cast fp32 [K][N] -> bf16 [N][K]. 32x32 tiles.
// ---------------------------------------------------------------------------
__global__ __launch_bounds__(256) void wcast_t(
    const float* __restrict__ wq, const float* __restrict__ wk,
    const float* __restrict__ wv, const float* __restrict__ wp,
    u16* __restrict__ tq, u16* __restrict__ tk,
    u16* __restrict__ tv, u16* __restrict__ tp)
{
    int z = blockIdx.z;
    const float* src = z == 0 ? wq : z == 1 ? wk : z == 2 ? wv : wp;
    u16* dst = z == 0 ? tq : z == 1 ? tk : z == 2 ? tv : tp;
    __shared__ float tile[32][33];
    int n0 = blockIdx.x * 32, k0 = blockIdx.y * 32;
    int tx = threadIdx.x & 31, ty = threadIdx.x >> 5;   // 32 x 8
    for (int i = 0; i < 4; i++)
        tile[ty + i * 8][tx] = src[(size_t)(k0 + ty + i * 8) * E_ + n0 + tx];
    __syncthreads();
    for (int i = 0; i < 4; i++)
        dst[(size_t)(n0 + ty + i * 8) * E_ + k0 + tx] = f2bf(tile[tx][ty + i * 8]);
}

// ---------------------------------------------------------------------------
// 8-phase 256x256 QKV GEMM (m201-style): 512 thr / 8 waves (2M x 4N), BK=64,
// wave tile 128x64 (8x4 frags, 64 MFMA/K-tile). Streams stacked along M:
// X = [qn;kn;vn] (12288 x 1024), W = [wtq;wtk;wtv] (3072 x 1024), z = by>>4.
// LDS 128KB double-buffered, rows 128B, chunk ^= (row&7) swizzle (attn-proven,
// both-sides involution). Counted vmcnt(2) once per K-tile (0 only at last),
// raw s_barrier (2 per K-tile) + compiler memory fences. B-frags in regs.
// Epilogue: z=0 q scatter (prescaled E^-0.5*log2e), z=1 k scatter,
// z=2 v transposed via per-wave LDS.
// ---------------------------------------------------------------------------
__global__ __launch_bounds__(512, 2) void gemm8ph(
    const u16* __restrict__ Xall, const u16* __restrict__ Wall,
    u16* __restrict__ qh, u16* __restrict__ kh, u16* __restrict__ vt)
{
    __shared__ __attribute__((aligned(16))) u16 lds[2][2][256 * 64]; // [buf][A/B]

    int lid = blockIdx.x + 4 * blockIdx.y;        // 192 blocks
    int swz = (lid & 7) * 24 + (lid >> 3);        // bijective XCD chunking
    int bx = swz & 3, by = swz >> 2;
    int z  = by >> 4;                             // stream 0/1/2

    int t = threadIdx.x, w = t >> 6, l = t & 63;
    int lr = l & 15, lg = l >> 4;
    int wm = w >> 2, wn = w & 3;
    int ris = l >> 3;                 // staging row within 8-row segment
    int csw = (l & 7) ^ ris;          // pre-swizzled source chunk
    int swk = lr & 7;                 // read-side swizzle key (row&7 == lr&7)

    const char* Xb = (const char*)Xall + (size_t)by * 256 * 2048;
    const char* Wb = (const char*)Wall + ((size_t)z * 1024 + (size_t)bx * 256) * 2048;

    f32x4 acc[8][4];
    f32x4 zero = {0.f, 0.f, 0.f, 0.f};
    #pragma unroll
    for (int i = 0; i < 8; i++)
        #pragma unroll
        for (int j = 0; j < 4; j++) acc[i][j] = zero;

    // stage group g of K-tile kt into buffer buf: wave w handles seg w*4+g
    // (8 rows x 128B) of both A and B => 2 gll16 per thread per group.
    auto stage = [&](int kt, int g, int buf) {
        int s = w * 4 + g;
        size_t rowoff = (size_t)(s * 8 + ris) * 2048;
        int koff = kt * 128 + csw * 16;
        gll16(Xb + rowoff + koff, (char*)&lds[buf][0][s * 512] + l * 16);
        gll16(Wb + rowoff + koff, (char*)&lds[buf][1][s * 512] + l * 16);
    };

    // prologue: tile 0 fully staged into buf 0 (8 loads/thread)
    for (int g = 0; g < 4; g++) stage(0, g, 0);

    const int NT = 16;                            // K=1024 / BK=64
    for (int kt = 0; kt < NT; kt++) {
        int cur = kt & 1, nxt = cur ^ 1;
        bool pre = (kt + 1 < NT);

        // ph0: issue first next-tile group BEFORE the wait, then counted wait:
        // queue = [tile kt: 8][tile kt+1: 2] -> vmcnt(2) retires tile kt.
        if (pre) {
            stage(kt + 1, 0, nxt);
            asm volatile("s_waitcnt vmcnt(2)" ::: "memory");
        } else {
            asm volatile("s_waitcnt vmcnt(0)" ::: "memory");
        }
        __builtin_amdgcn_s_barrier();
        asm volatile("" ::: "memory");

        const u16* As = &lds[cur][0][0];
        const u16* Bs = &lds[cur][1][0];

        // B fragments once per K-tile, held in registers (32 VGPR)
        bf16x8 bfr[4][2];
        #pragma unroll
        for (int nf = 0; nf < 4; nf++)
            #pragma unroll
            for (int kk = 0; kk < 2; kk++)
                bfr[nf][kk] = *(const bf16x8*)
                    &Bs[(wn * 64 + nf * 16 + lr) * 64 + ((kk * 4 + lg) ^ swk) * 8];

        #pragma unroll
        for (int g = 0; g < 4; g++) {
            if (g && pre) stage(kt + 1, g, nxt);
            bf16x8 af[2][2];
            #pragma unroll
            for (int i = 0; i < 2; i++)
                #pragma unroll
                for (int kk = 0; kk < 2; kk++)
                    af[i][kk] = *(const bf16x8*)
                        &As[(wm * 128 + (g * 2 + i) * 16 + lr) * 64 +
                            ((kk * 4 + lg) ^ swk) * 8];
            __builtin_amdgcn_s_setprio(1);
            #pragma unroll
            for (int i = 0; i < 2; i++)
                #pragma unroll
                for (int nf = 0; nf < 4; nf++)
                    #pragma unroll
                    for (int kk = 0; kk < 2; kk++)
                        acc[g * 2 + i][nf] = __builtin_amdgcn_mfma_f32_16x16x32_bf16(
                            af[i][kk], bfr[nf][kk], acc[g * 2 + i][nf], 0, 0, 0);
            __builtin_amdgcn_s_setprio(0);
        }
        asm volatile("" ::: "memory");
        __builtin_amdgcn_s_barrier();
    }

    if (z < 2) {
        u16* outB = z == 0 ? qh : kh;
        float sc = z == 0 ? 0.04508422f : 1.0f;   // E^-0.5 * log2e folded into q
        #pragma unroll
        for (int mg = 0; mg < 8; mg++)
            #pragma unroll
            for (int nf = 0; nf < 4; nf++)
                #pragma unroll
                for (int r = 0; r < 4; r++) {
                    int mrow = (by & 15) * 256 + wm * 128 + mg * 16 + lg * 4 + r;
                    int col  = bx * 256 + wn * 64 + nf * 16 + lr;
                    int bb = mrow >> 10, tt = mrow & 1023;
                    int hh = col >> 6, dd = col & 63;
                    outB[(((size_t)(bb * H_ + hh)) * T_ + tt) * HS_ + dd] =
                        f2bf(acc[mg][nf][r] * sc);
                }
    } else {
        // V: per-wave transpose through LDS (dead after K-loop), 2 half-passes
        __syncthreads();
        u16* Tt = &lds[0][0][0] + w * 4608;        // [64 d][72] u16 per wave
        int hh = bx * 4 + wn;
        u16* outV = vt + ((size_t)(((by & 15) * 256 + wm * 128) >> 10) * H_ + hh)
                         * HS_ * T_;
        #pragma unroll
        for (int half = 0; half < 2; half++) {
            #pragma unroll
            for (int mg2 = 0; mg2 < 4; mg2++)
                #pragma unroll
                for (int nf = 0; nf < 4; nf++)
                    #pragma unroll
                    for (int r = 0; r < 4; r++)
                        Tt[(nf * 16 + lr) * 72 + mg2 * 16 + lg * 4 + r] =
                            f2bf(acc[half * 4 + mg2][nf][r]);
            int mbase = (by & 15) * 256 + wm * 128 + half * 64;
            int tbase = mbase & 1023;
            int dl = l >> 3, tc = l & 7;
            #pragma unroll
            for (int u = 0; u < 8; u++) {
                int d = u * 8 + dl;
                bf16x8 vv = *(const bf16x8*)&Tt[d * 72 + tc * 8];
                *(bf16x8*)&outV[(size_t)d * T_ + tbase + tc * 8] = vv;
            }
        }
    }
}

// ---------------------------------------------------------------------------
// GEMM C[128 x 128] tile (m97 structure) -- used for the final projection.
// Double-buffered BK=32; LDS swizzle chunk ^= (row>>1)&3; pre-swizzled global
// source; XCD-chunked blockIdx swizzle. f32 out + bias.
// ---------------------------------------------------------------------------
__global__ __launch_bounds__(256) void gemm128(
    const u16* __restrict__ X, const u16* __restrict__ Wt,
    float* __restrict__ outF, const float* __restrict__ bias)
{
    __shared__ __attribute__((aligned(16))) char smem[32768];
    int lid = blockIdx.x + 8 * blockIdx.y;    // 256 blocks
    int swz = (lid & 7) * 32 + (lid >> 3);
    int bx = swz & 7;
    int by = swz >> 3;

    const int K = 1024;
    int n0 = bx * 128, m0 = by * 128;
    int t = threadIdx.x, w = t >> 6, l = t & 63;
    int lr = l & 15, lg = l >> 4, wm = w >> 1, wn = w & 1;

    f32x4 acc[4][4];
    f32x4 zero = {0.f, 0.f, 0.f, 0.f};
    for (int i = 0; i < 4; i++)
        for (int j = 0; j < 4; j++) acc[i][j] = zero;

    const char* Xb = (const char*)X + (size_t)m0 * 2048;
    const char* Wb = (const char*)Wt + (size_t)n0 * 2048;

    int scol = ((l & 3) ^ ((l >> 3) & 3)) * 16;

    auto stage = [&](int k0, int buf) {
        int kb = k0 * 2;
        for (int j = 0; j < 2; j++) {
            int seg = w * 2 + j;
            int row = seg * 16 + (l >> 2);
            gll16(Xb + (size_t)row * 2048 + kb + scol,
                  smem + buf * 8192 + seg * 1024 + l * 16);
            gll16(Wb + (size_t)row * 2048 + kb + scol,
                  smem + 16384 + buf * 8192 + seg * 1024 + l * 16);
        }
    };

    stage(0, 0);
    __syncthreads();
    int b = 0;
    int swr = (lr >> 1) & 3;
    for (int k0 = 0; k0 < K; k0 += 32) {
        if (k0 + 32 < K) stage(k0 + 32, b ^ 1);
        const u16* As = (const u16*)(smem + b * 8192);
        const u16* Bs = (const u16*)(smem + 16384 + b * 8192);
        bf16x8 af[4], bfr[4];
        for (int i = 0; i < 4; i++)
            af[i] = *(const bf16x8*)&As[(wm * 64 + i * 16 + lr) * 32 + (lg ^ swr) * 8];
        for (int j = 0; j < 4; j++)
            bfr[j] = *(const bf16x8*)&Bs[(wn * 64 + j * 16 + lr) * 32 + (lg ^ swr) * 8];
        for (int i = 0; i < 4; i++)
            for (int j = 0; j < 4; j++)
                acc[i][j] = __builtin_amdgcn_mfma_f32_16x16x32_bf16(
                    af[i], bfr[j], acc[i][j], 0, 0, 0);
        __syncthreads();
        b ^= 1;
    }

    for (int i = 0; i < 4; i++)
        for (int j = 0; j < 4; j++)
            for (int r = 0; r < 4; r++) {
                int row = m0 + wm * 64 + i * 16 + lg * 4 + r;
                int col = n0 + wn * 64 + j * 16 + lr;
                outF[(size_t)row * E_ + col] = acc[i][j][r] + bias[col];
            }
}

// ---------------------------------------------------------------------------
// Flash attention, causal. Block = 128 q-rows (wave owns 32), grid (8,64).
// Double-buffered K/V LDS staging (XOR-swizzled both sides), one barrier per
// 64-key tile, 32 MFMA/tile/wave. Softmax in exp2 units (log2e folded into
// Q): NATIVE v_exp_f32 only. Defer-max (THR=11.5 log2 = 8 nat), cheap
// ties-away bf16 round for P, rcp-mul epilogue. XCD-chunked block swizzle.
// ---------------------------------------------------------------------------
__global__ __launch_bounds__(256) void attn(
    const u16* __restrict__ Qh, const u16* __restrict__ Kh,
    const u16* __restrict__ Vt, u16* __restrict__ Out)
{
    int lid = blockIdx.x + 8 * blockIdx.y;        // 512 blocks
    int swz = (lid & 7) * 64 + (lid >> 3);
    int qt = 7 - (swz & 7);                       // heavy tiles first
    int bh = swz >> 3;
    int b = bh >> 4, h = bh & 15;
    int t = threadIdx.x, w = t >> 6, l = t & 63;
    int lr = l & 15, lg = l >> 4;
    int sw = lr & 7;                              // read-side swizzle key

    __shared__ __attribute__((aligned(16))) u16 Ks[2][4096];
    __shared__ __attribute__((aligned(16))) u16 Vs[2][4096];
    __shared__ __attribute__((aligned(16))) u16 Ps[4][2048];

    const char* Kb = (const char*)(Kh + (size_t)bh * T_ * HS_);
    const char* Vb = (const char*)(Vt + (size_t)bh * HS_ * T_);
    const u16*  Qb = Qh + (size_t)bh * T_ * HS_;

    int ris = l >> 3;
    int csw = (l & 7) ^ ris;

    bf16x8 qf[2][2];
    for (int i = 0; i < 2; i++) {
        int qrow = qt * 128 + w * 32 + i * 16 + lr;
        qf[i][0] = *(const bf16x8*)&Qb[qrow * 64 + lg * 8];
        qf[i][1] = *(const bf16x8*)&Qb[qrow * 64 + 32 + lg * 8];
    }

    f32x4 zero = {0.f, 0.f, 0.f, 0.f};
    f32x4 o[2][4];
    float m[2][4], psum[2][4];
    for (int i = 0; i < 2; i++)
        for (int nf = 0; nf < 4; nf++) o[i][nf] = zero;
    for (int i = 0; i < 2; i++)
        for (int r = 0; r < 4; r++) { m[i][r] = -1e30f; psum[i][r] = 0.f; }

    int nkv = 2 * qt + 2;

    auto stageKV = [&](int kt2, int bsel) {
        int kv0 = kt2 * 64;
        for (int j = 0; j < 2; j++) {
            int seg = w * 2 + j;
            int row = seg * 8 + ris;
            gll16(Kb + (size_t)(kv0 + row) * 128 + csw * 16,
                  (char*)Ks[bsel] + seg * 1024);
            gll16(Vb + (size_t)row * 2048 + (size_t)kv0 * 2 + csw * 16,
                  (char*)Vs[bsel] + seg * 1024);
        }
    };

    stageKV(0, 0);
    __syncthreads();
    int bsel = 0;

    for (int kt = 0; kt < nkv; kt++) {
        if (kt + 1 < nkv) stageKV(kt + 1, bsel ^ 1);

        int kv0 = kt * 64;
        const u16* Kl = Ks[bsel];
        const u16* Vl = Vs[bsel];

        f32x4 s[2][4];
        __builtin_amdgcn_s_setprio(1);
        for (int kf = 0; kf < 4; kf++) {
            int key = kf * 16 + lr;
            bf16x8 bk0 = *(const bf16x8*)&Kl[key * 64 + (lg ^ sw) * 8];
            bf16x8 bk1 = *(const bf16x8*)&Kl[key * 64 + ((lg + 4) ^ sw) * 8];
            for (int i = 0; i < 2; i++) {
                s[i][kf] = __builtin_amdgcn_mfma_f32_16x16x32_bf16(qf[i][0], bk0, zero, 0, 0, 0);
                s[i][kf] = __builtin_amdgcn_mfma_f32_16x16x32_bf16(qf[i][1], bk1, s[i][kf], 0, 0, 0);
            }
        }
        __builtin_amdgcn_s_setprio(0);

        if (kt >= 2 * qt) {
            for (int i = 0; i < 2; i++)
                for (int kf = 0; kf < 4; kf++)
                    for (int r = 0; r < 4; r++) {
                        int key = kv0 + kf * 16 + lr;
                        int qr  = qt * 128 + w * 32 + i * 16 + lg * 4 + r;
                        if (key > qr) s[i][kf][r] = -1e30f;
                    }
        }

        float pmr[2][4];
        bool ok = true;
        for (int i = 0; i < 2; i++)
            for (int r = 0; r < 4; r++) {
                pmr[i][r] = fmaxf(fmaxf(s[i][0][r], s[i][1][r]),
                                  fmaxf(s[i][2][r], s[i][3][r]));
                ok &= (pmr[i][r] <= m[i][r] + 11.5f);
            }
        if (!__all(ok)) {
            for (int i = 0; i < 2; i++)
                for (int r = 0; r < 4; r++) {
                    float mt = pmr[i][r];
                    for (int off = 1; off < 16; off <<= 1)
                        mt = fmaxf(mt, __shfl_xor(mt, off, 64));
                    float mn = fmaxf(m[i][r], mt);
                    float al = fexp2(m[i][r] - mn);
                    m[i][r] = mn;
                    psum[i][r] *= al;
                    for (int nf = 0; nf < 4; nf++) o[i][nf][r] *= al;
                }
        }

        for (int i = 0; i < 2; i++)
            for (int kf = 0; kf < 4; kf++)
                for (int r = 0; r < 4; r++) {
                    float p = fexp2(s[i][kf][r] - m[i][r]);
                    psum[i][r] += p;
                    int row = i * 16 + lg * 4 + r;
                    int ch  = (kf * 2 + (lr >> 3)) ^ (row & 7);
                    Ps[w][row * 64 + ch * 8 + sw] = f2bf_fast(p);
                }

        __builtin_amdgcn_s_setprio(1);
        for (int ks = 0; ks < 2; ks++) {
            bf16x8 pa0 = *(const bf16x8*)&Ps[w][(lr) * 64 + ((ks * 4 + lg) ^ sw) * 8];
            bf16x8 pa1 = *(const bf16x8*)&Ps[w][(16 + lr) * 64 + ((ks * 4 + lg) ^ sw) * 8];
            for (int nf = 0; nf < 4; nf++) {
                int d = nf * 16 + lr;
                bf16x8 bv = *(const bf16x8*)&Vl[d * 64 + ((ks * 4 + lg) ^ sw) * 8];
                o[0][nf] = __builtin_amdgcn_mfma_f32_16x16x32_bf16(pa0, bv, o[0][nf], 0, 0, 0);
                o[1][nf] = __builtin_amdgcn_mfma_f32_16x16x32_bf16(pa1, bv, o[1][nf], 0, 0, 0);
            }
        }
        __builtin_amdgcn_s_setprio(0);
        __syncthreads();
        bsel ^= 1;
    }

    for (int i = 0; i < 2; i++)
        for (int r = 0; r < 4; r++) {
            for (int off = 1; off < 16; off <<= 1)
                psum[i][r] += __shfl_xor(psum[i][r], off, 64);
            psum[i][r] = frcp(psum[i][r]);
        }

    for (int i = 0; i < 2; i++)
        for (int nf = 0; nf < 4; nf++)
            for (int r = 0; r < 4; r++) {
                int row = qt * 128 + w * 32 + i * 16 + lg * 4 + r;
                int col = h * 64 + nf * 16 + lr;
                Out[((size_t)(b * T_ + row)) * E_ + col] = f2bf(o[i][nf][r] * psum[i][r]);
            }
}

// ---------------------------------------------------------------------------
extern "C" void kernel_launch(void* const* d_in, const int* in_sizes, int n_in,
                              void* d_out, int out_size, void* d_ws, size_t ws_size,
                              hipStream_t stream) {
    const float* v  = (const float*)d_in[0];
    const float* k  = (const float*)d_in[1];
    const float* q  = (const float*)d_in[2];
    const float* g  = (const float*)d_in[3];
    const float* be = (const float*)d_in[4];
    const float* Wq = (const float*)d_in[5];
    const float* Wk = (const float*)d_in[6];
    const float* Wv = (const float*)d_in[7];
    const float* Wp = (const float*)d_in[8];
    const float* bp = (const float*)d_in[9];
    float* out = (float*)d_out;

    // NOTE: no backslashes at end of comments (r11 compile failure: a
    // trailing backslash in a // comment line-continues into the next
    // declaration and deletes it).
    char* ws = (char*)d_ws;
    u16* qh  = (u16*)(ws);                // 8MB [B,H,T,64] (pre-scaled)
    u16* kh  = (u16*)(ws + (8u  << 20));  // 8MB [B,H,T,64]
    u16* vt  = (u16*)(ws + (16u << 20));  // 8MB [B,H,64,T]
    u16* qn  = (u16*)(ws + (24u << 20));  // 8MB [B,T,E] -- contiguous with kn,vn
    u16* kn  = (u16*)(ws + (32u << 20));  // 8MB
    u16* vn  = (u16*)(ws + (40u << 20));  // 8MB
    u16* wtq = (u16*)(ws + (48u << 20));  // 2MB each, contiguous stack
    u16* wtk = (u16*)(ws + (50u << 20));
    u16* wtv = (u16*)(ws + (52u << 20));
    u16* wtp = (u16*)(ws + (54u << 20));
    u16* ao  = (u16*)(ws + (24u << 20));  // alias qn (dead after projections)

    hipLaunchKernelGGL(wcast_t, dim3(32, 32, 4), dim3(256), 0, stream,
                       Wq, Wk, Wv, Wp, wtq, wtk, wtv, wtp);
    hipLaunchKernelGGL(ln_all, dim3(3 * BT_), dim3(256), 0, stream,
                       v, k, q, g, be, vn, kn, qn);
    hipLaunchKernelGGL(gemm8ph, dim3(4, 48), dim3(512), 0, stream,
                       qn, wtq, qh, kh, vt);
    hipLaunchKernelGGL(attn, dim3(8, 64), dim3(256), 0, stream,
                       qh, kh, vt, ao);
    hipLaunchKernelGGL(gemm128, dim3(8, 32), dim3(256), 0, stream,
                       ao, wtp, out, bp);
}

// Round 13
// 198.187 us; speedup vs baseline: 1.0914x; 1.0231x over previous
//
#include <hip/hip_runtime.h>
#include <stdint.h>

#define B_ 4
#define T_ 1024
#define E_ 1024
#define H_ 16
#define HS_ 64
#define BT_ 4096

typedef unsigned short u16;
typedef __attribute__((ext_vector_type(8))) short bf16x8;
typedef __attribute__((ext_vector_type(4))) float f32x4;

__device__ __forceinline__ u16 f2bf(float f) {
    unsigned u = __float_as_uint(f);
    u += 0x7fff + ((u >> 16) & 1);   // round-to-nearest-even
    return (u16)(u >> 16);
}

__device__ __forceinline__ u16 f2bf_fast(float f) {
    // round-to-nearest (ties away); 2 VALU ops vs 4 for RNE
    return (u16)((__float_as_uint(f) + 0x8000u) >> 16);
}

// NATIVE hw exp2 (single v_exp_f32). exp2f() is the OCML libm routine with a
// denormal fixup branch -- measured +13us regression in r9. Do not use it.
__device__ __forceinline__ float fexp2(float x) {
#if __has_builtin(__builtin_amdgcn_exp2f)
    return __builtin_amdgcn_exp2f(x);
#else
    float r; asm("v_exp_f32 %0, %1" : "=v"(r) : "v"(x)); return r;
#endif
}

__device__ __forceinline__ float frcp(float x) {
#if __has_builtin(__builtin_amdgcn_rcpf)
    return __builtin_amdgcn_rcpf(x);
#else
    float r; asm("v_rcp_f32 %0, %1" : "=v"(r) : "v"(x)); return r;
#endif
}

__device__ __forceinline__ void gll16(const void* g, void* l) {
    __builtin_amdgcn_global_load_lds(
        (const __attribute__((address_space(1))) unsigned int*)g,
        (__attribute__((address_space(3))) unsigned int*)l, 16, 0, 0);
}

// ---------------------------------------------------------------------------
// LayerNorm for all three streams. One block (256 thr) per row of 1024.
// ---------------------------------------------------------------------------
__global__ __launch_bounds__(256) void ln_all(
    const float* __restrict__ v, const float* __restrict__ k,
    const float* __restrict__ q, const float* __restrict__ g,
    const float* __restrict__ b,
    u16* __restrict__ vn, u16* __restrict__ kn, u16* __restrict__ qn)
{
    int row = blockIdx.x;
    int which = row >> 12;
    int r = row & 4095;
    const float* src = which == 0 ? v : which == 1 ? k : q;
    u16* dst = which == 0 ? vn : which == 1 ? kn : qn;

    int t = threadIdx.x;
    float4 x = ((const float4*)(src + (size_t)r * E_))[t];
    float s  = x.x + x.y + x.z + x.w;
    float ss = x.x * x.x + x.y * x.y + x.z * x.z + x.w * x.w;
    for (int off = 32; off; off >>= 1) {
        s  += __shfl_down(s, off, 64);
        ss += __shfl_down(ss, off, 64);
    }
    __shared__ float red[8];
    int w = t >> 6, l = t & 63;
    if (l == 0) { red[w] = s; red[4 + w] = ss; }
    __syncthreads();
    float fs  = red[0] + red[1] + red[2] + red[3];
    float fss = red[4] + red[5] + red[6] + red[7];
    float mu  = fs * (1.0f / E_);
    float var = fss * (1.0f / E_) - mu * mu;
    float rstd = rsqrtf(var + 1e-5f);

    float4 gg = ((const float4*)g)[t];
    float4 bb = ((const float4*)b)[t];
    ushort4 o;
    o.x = f2bf((x.x - mu) * rstd * gg.x + bb.x);
    o.y = f2bf((x.y - mu) * rstd * gg.y + bb.y);
    o.z = f2bf((x.z - mu) * rstd * gg.z + bb.z);
    o.w = f2bf((x.w - mu) * rstd * gg.w + bb.w);
    ((ushort4*)(dst + (size_t)r * E_))[t] = o;
}

// ---------------------------------------------------------------------------
// Transpose + cast fp32 [K][N] -> bf16 [N][K]. 32x32 tiles.
// ---------------------------------------------------------------------------
__global__ __launch_bounds__(256) void wcast_t(
    const float* __restrict__ wq, const float* __restrict__ wk,
    const float* __restrict__ wv, const float* __restrict__ wp,
    u16* __restrict__ tq, u16* __restrict__ tk,
    u16* __restrict__ tv, u16* __restrict__ tp)
{
    int z = blockIdx.z;
    const float* src = z == 0 ? wq : z == 1 ? wk : z == 2 ? wv : wp;
    u16* dst = z == 0 ? tq : z == 1 ? tk : z == 2 ? tv : tp;
    __shared__ float tile[32][33];
    int n0 = blockIdx.x * 32, k0 = blockIdx.y * 32;
    int tx = threadIdx.x & 31, ty = threadIdx.x >> 5;   // 32 x 8
    for (int i = 0; i < 4; i++)
        tile[ty + i * 8][tx] = src[(size_t)(k0 + ty + i * 8) * E_ + n0 + tx];
    __syncthreads();
    for (int i = 0; i < 4; i++)
        dst[(size_t)(n0 + ty + i * 8) * E_ + k0 + tx] = f2bf(tile[tx][ty + i * 8]);
}

// ---------------------------------------------------------------------------
// 8-phase 256x256 QKV GEMM (m201-style): 512 thr / 8 waves (2M x 4N), BK=64,
// wave tile 128x64 (8x4 frags, 64 MFMA/K-tile). Streams stacked along M:
// X = [qn;kn;vn] (12288 x 1024), W = [wtq;wtk;wtv] (3072 x 1024), z = by>>4.
// LDS 128KB double-buffered, rows 128B, chunk ^= (row&7) swizzle. Counted
// vmcnt(2) once per K-tile (0 only at last), raw s_barrier + fences.
// ---------------------------------------------------------------------------
__global__ __launch_bounds__(512, 2) void gemm8ph(
    const u16* __restrict__ Xall, const u16* __restrict__ Wall,
    u16* __restrict__ qh, u16* __restrict__ kh, u16* __restrict__ vt)
{
    __shared__ __attribute__((aligned(16))) u16 lds[2][2][256 * 64]; // [buf][A/B]

    int lid = blockIdx.x + 4 * blockIdx.y;        // 192 blocks
    int swz = (lid & 7) * 24 + (lid >> 3);        // bijective XCD chunking
    int bx = swz & 3, by = swz >> 2;
    int z  = by >> 4;                             // stream 0/1/2

    int t = threadIdx.x, w = t >> 6, l = t & 63;
    int lr = l & 15, lg = l >> 4;
    int wm = w >> 2, wn = w & 3;
    int ris = l >> 3;                 // staging row within 8-row segment
    int csw = (l & 7) ^ ris;          // pre-swizzled source chunk
    int swk = lr & 7;                 // read-side swizzle key (row&7 == lr&7)

    const char* Xb = (const char*)Xall + (size_t)by * 256 * 2048;
    const char* Wb = (const char*)Wall + ((size_t)z * 1024 + (size_t)bx * 256) * 2048;

    f32x4 acc[8][4];
    f32x4 zero = {0.f, 0.f, 0.f, 0.f};
    #pragma unroll
    for (int i = 0; i < 8; i++)
        #pragma unroll
        for (int j = 0; j < 4; j++) acc[i][j] = zero;

    auto stage = [&](int kt, int g, int buf) {
        int s = w * 4 + g;
        size_t rowoff = (size_t)(s * 8 + ris) * 2048;
        int koff = kt * 128 + csw * 16;
        gll16(Xb + rowoff + koff, (char*)&lds[buf][0][s * 512] + l * 16);
        gll16(Wb + rowoff + koff, (char*)&lds[buf][1][s * 512] + l * 16);
    };

    for (int g = 0; g < 4; g++) stage(0, g, 0);

    const int NT = 16;                            // K=1024 / BK=64
    for (int kt = 0; kt < NT; kt++) {
        int cur = kt & 1, nxt = cur ^ 1;
        bool pre = (kt + 1 < NT);

        if (pre) {
            stage(kt + 1, 0, nxt);
            asm volatile("s_waitcnt vmcnt(2)" ::: "memory");
        } else {
            asm volatile("s_waitcnt vmcnt(0)" ::: "memory");
        }
        __builtin_amdgcn_s_barrier();
        asm volatile("" ::: "memory");

        const u16* As = &lds[cur][0][0];
        const u16* Bs = &lds[cur][1][0];

        bf16x8 bfr[4][2];
        #pragma unroll
        for (int nf = 0; nf < 4; nf++)
            #pragma unroll
            for (int kk = 0; kk < 2; kk++)
                bfr[nf][kk] = *(const bf16x8*)
                    &Bs[(wn * 64 + nf * 16 + lr) * 64 + ((kk * 4 + lg) ^ swk) * 8];

        #pragma unroll
        for (int g = 0; g < 4; g++) {
            if (g && pre) stage(kt + 1, g, nxt);
            bf16x8 af[2][2];
            #pragma unroll
            for (int i = 0; i < 2; i++)
                #pragma unroll
                for (int kk = 0; kk < 2; kk++)
                    af[i][kk] = *(const bf16x8*)
                        &As[(wm * 128 + (g * 2 + i) * 16 + lr) * 64 +
                            ((kk * 4 + lg) ^ swk) * 8];
            __builtin_amdgcn_s_setprio(1);
            #pragma unroll
            for (int i = 0; i < 2; i++)
                #pragma unroll
                for (int nf = 0; nf < 4; nf++)
                    #pragma unroll
                    for (int kk = 0; kk < 2; kk++)
                        acc[g * 2 + i][nf] = __builtin_amdgcn_mfma_f32_16x16x32_bf16(
                            af[i][kk], bfr[nf][kk], acc[g * 2 + i][nf], 0, 0, 0);
            __builtin_amdgcn_s_setprio(0);
        }
        asm volatile("" ::: "memory");
        __builtin_amdgcn_s_barrier();
    }

    if (z < 2) {
        u16* outB = z == 0 ? qh : kh;
        float sc = z == 0 ? 0.04508422f : 1.0f;   // E^-0.5 * log2e folded into q
        #pragma unroll
        for (int mg = 0; mg < 8; mg++)
            #pragma unroll
            for (int nf = 0; nf < 4; nf++)
                #pragma unroll
                for (int r = 0; r < 4; r++) {
                    int mrow = (by & 15) * 256 + wm * 128 + mg * 16 + lg * 4 + r;
                    int col  = bx * 256 + wn * 64 + nf * 16 + lr;
                    int bb = mrow >> 10, tt = mrow & 1023;
                    int hh = col >> 6, dd = col & 63;
                    outB[(((size_t)(bb * H_ + hh)) * T_ + tt) * HS_ + dd] =
                        f2bf(acc[mg][nf][r] * sc);
                }
    } else {
        // V: per-wave transpose through LDS (dead after K-loop), 2 half-passes
        __syncthreads();
        u16* Tt = &lds[0][0][0] + w * 4608;        // [64 d][72] u16 per wave
        int hh = bx * 4 + wn;
        u16* outV = vt + ((size_t)(((by & 15) * 256 + wm * 128) >> 10) * H_ + hh)
                         * HS_ * T_;
        #pragma unroll
        for (int half = 0; half < 2; half++) {
            #pragma unroll
            for (int mg2 = 0; mg2 < 4; mg2++)
                #pragma unroll
                for (int nf = 0; nf < 4; nf++)
                    #pragma unroll
                    for (int r = 0; r < 4; r++)
                        Tt[(nf * 16 + lr) * 72 + mg2 * 16 + lg * 4 + r] =
                            f2bf(acc[half * 4 + mg2][nf][r]);
            int mbase = (by & 15) * 256 + wm * 128 + half * 64;
            int tbase = mbase & 1023;
            int dl = l >> 3, tc = l & 7;
            #pragma unroll
            for (int u = 0; u < 8; u++) {
                int d = u * 8 + dl;
                bf16x8 vv = *(const bf16x8*)&Tt[d * 72 + tc * 8];
                *(bf16x8*)&outV[(size_t)d * T_ + tbase + tc * 8] = vv;
            }
        }
    }
}

// ---------------------------------------------------------------------------
// GEMM C[128 x 128] tile (m97 structure) -- final projection. f32 out + bias.
// ---------------------------------------------------------------------------
__global__ __launch_bounds__(256) void gemm128(
    const u16* __restrict__ X, const u16* __restrict__ Wt,
    float* __restrict__ outF, const float* __restrict__ bias)
{
    __shared__ __attribute__((aligned(16))) char smem[32768];
    int lid = blockIdx.x + 8 * blockIdx.y;    // 256 blocks
    int swz = (lid & 7) * 32 + (lid >> 3);
    int bx = swz & 7;
    int by = swz >> 3;

    const int K = 1024;
    int n0 = bx * 128, m0 = by * 128;
    int t = threadIdx.x, w = t >> 6, l = t & 63;
    int lr = l & 15, lg = l >> 4, wm = w >> 1, wn = w & 1;

    f32x4 acc[4][4];
    f32x4 zero = {0.f, 0.f, 0.f, 0.f};
    for (int i = 0; i < 4; i++)
        for (int j = 0; j < 4; j++) acc[i][j] = zero;

    const char* Xb = (const char*)X + (size_t)m0 * 2048;
    const char* Wb = (const char*)Wt + (size_t)n0 * 2048;

    int scol = ((l & 3) ^ ((l >> 3) & 3)) * 16;

    auto stage = [&](int k0, int buf) {
        int kb = k0 * 2;
        for (int j = 0; j < 2; j++) {
            int seg = w * 2 + j;
            int row = seg * 16 + (l >> 2);
            gll16(Xb + (size_t)row * 2048 + kb + scol,
                  smem + buf * 8192 + seg * 1024 + l * 16);
            gll16(Wb + (size_t)row * 2048 + kb + scol,
                  smem + 16384 + buf * 8192 + seg * 1024 + l * 16);
        }
    };

    stage(0, 0);
    __syncthreads();
    int b = 0;
    int swr = (lr >> 1) & 3;
    for (int k0 = 0; k0 < K; k0 += 32) {
        if (k0 + 32 < K) stage(k0 + 32, b ^ 1);
        const u16* As = (const u16*)(smem + b * 8192);
        const u16* Bs = (const u16*)(smem + 16384 + b * 8192);
        bf16x8 af[4], bfr[4];
        for (int i = 0; i < 4; i++)
            af[i] = *(const bf16x8*)&As[(wm * 64 + i * 16 + lr) * 32 + (lg ^ swr) * 8];
        for (int j = 0; j < 4; j++)
            bfr[j] = *(const bf16x8*)&Bs[(wn * 64 + j * 16 + lr) * 32 + (lg ^ swr) * 8];
        for (int i = 0; i < 4; i++)
            for (int j = 0; j < 4; j++)
                acc[i][j] = __builtin_amdgcn_mfma_f32_16x16x32_bf16(
                    af[i], bfr[j], acc[i][j], 0, 0, 0);
        __syncthreads();
        b ^= 1;
    }

    for (int i = 0; i < 4; i++)
        for (int j = 0; j < 4; j++)
            for (int r = 0; r < 4; r++) {
                int row = m0 + wm * 64 + i * 16 + lg * 4 + r;
                int col = n0 + wn * 64 + j * 16 + lr;
                outF[(size_t)row * E_ + col] = acc[i][j][r] + bias[col];
            }
}

// ---------------------------------------------------------------------------
// Flash attention, causal. Block = 128 q-rows, 512 thr / 8 WAVES of 16 rows
// (r13: doubles waves/CU to 16 = 4/SIMD for latency hiding; attn was
// latency-bound at 11.8% occupancy with 4-wave blocks). grid (8,64) = 512
// blocks, 2 blocks/CU (LDS 48KB). psum now accumulated by an extra MFMA
// with an all-ones B fragment (deletes 32 VALU adds/tile + final shuffle
// reduce). Double-buffered K/V staging (XOR-swizzled), exp2-softmax with
// native v_exp, defer-max THR=11.5, XCD-chunked swizzle, heavy-first.
// ---------------------------------------------------------------------------
__global__ __launch_bounds__(512, 4) void attn(
    const u16* __restrict__ Qh, const u16* __restrict__ Kh,
    const u16* __restrict__ Vt, u16* __restrict__ Out)
{
    int lid = blockIdx.x + 8 * blockIdx.y;        // 512 blocks
    int swz = (lid & 7) * 64 + (lid >> 3);
    int qt = 7 - (swz & 7);                       // heavy tiles first
    int bh = swz >> 3;
    int b = bh >> 4, h = bh & 15;
    int t = threadIdx.x, w = t >> 6, l = t & 63;  // w in 0..7
    int lr = l & 15, lg = l >> 4;
    int sw = lr & 7;                              // read-side swizzle key

    __shared__ __attribute__((aligned(16))) u16 Ks[2][4096];
    __shared__ __attribute__((aligned(16))) u16 Vs[2][4096];
    __shared__ __attribute__((aligned(16))) u16 Ps[8][1024];

    const char* Kb = (const char*)(Kh + (size_t)bh * T_ * HS_);
    const char* Vb = (const char*)(Vt + (size_t)bh * HS_ * T_);
    const u16*  Qb = Qh + (size_t)bh * T_ * HS_;

    int ris = l >> 3;                  // staging row within 8-row segment
    int csw = (l & 7) ^ ris;           // pre-swizzled source chunk

    int qrow = qt * 128 + w * 16 + lr;
    bf16x8 qf0 = *(const bf16x8*)&Qb[qrow * 64 + lg * 8];
    bf16x8 qf1 = *(const bf16x8*)&Qb[qrow * 64 + 32 + lg * 8];

    bf16x8 onesb;                      // bf16 1.0 x8 for psum-by-MFMA
    #pragma unroll
    for (int j = 0; j < 8; j++) onesb[j] = (short)0x3F80;

    f32x4 zero = {0.f, 0.f, 0.f, 0.f};
    f32x4 o[4], ps;
    float m[4];
    for (int nf = 0; nf < 4; nf++) o[nf] = zero;
    ps = zero;
    for (int r = 0; r < 4; r++) m[r] = -1e30f;

    int nkv = 2 * qt + 2;

    // each of the 8 waves stages one 8-row segment of K and of V
    auto stageKV = [&](int kt2, int bsel) {
        int kv0 = kt2 * 64;
        int row = w * 8 + ris;
        gll16(Kb + (size_t)(kv0 + row) * 128 + csw * 16,
              (char*)Ks[bsel] + w * 1024);
        gll16(Vb + (size_t)row * 2048 + (size_t)kv0 * 2 + csw * 16,
              (char*)Vs[bsel] + w * 1024);
    };

    stageKV(0, 0);
    __syncthreads();
    int bsel = 0;

    for (int kt = 0; kt < nkv; kt++) {
        if (kt + 1 < nkv) stageKV(kt + 1, bsel ^ 1);

        int kv0 = kt * 64;
        const u16* Kl = Ks[bsel];
        const u16* Vl = Vs[bsel];

        // S = Q K^T : 8 MFMA per wave (16 q-rows x 64 keys)
        f32x4 s[4];
        __builtin_amdgcn_s_setprio(1);
        for (int kf = 0; kf < 4; kf++) {
            int key = kf * 16 + lr;
            bf16x8 bk0 = *(const bf16x8*)&Kl[key * 64 + (lg ^ sw) * 8];
            bf16x8 bk1 = *(const bf16x8*)&Kl[key * 64 + ((lg + 4) ^ sw) * 8];
            s[kf] = __builtin_amdgcn_mfma_f32_16x16x32_bf16(qf0, bk0, zero, 0, 0, 0);
            s[kf] = __builtin_amdgcn_mfma_f32_16x16x32_bf16(qf1, bk1, s[kf], 0, 0, 0);
        }
        __builtin_amdgcn_s_setprio(0);

        if (kt >= 2 * qt) {            // last two tiles touch the diagonal
            for (int kf = 0; kf < 4; kf++)
                for (int r = 0; r < 4; r++) {
                    int key = kv0 + kf * 16 + lr;
                    int qr  = qt * 128 + w * 16 + lg * 4 + r;
                    if (key > qr) s[kf][r] = -1e30f;
                }
        }

        // defer-max: per-lane max + wave vote (rarely rescales)
        float pmr[4];
        bool ok = true;
        for (int r = 0; r < 4; r++) {
            pmr[r] = fmaxf(fmaxf(s[0][r], s[1][r]), fmaxf(s[2][r], s[3][r]));
            ok &= (pmr[r] <= m[r] + 11.5f);
        }
        if (!__all(ok)) {
            for (int r = 0; r < 4; r++) {
                float mt = pmr[r];
                for (int off = 1; off < 16; off <<= 1)
                    mt = fmaxf(mt, __shfl_xor(mt, off, 64));
                float mn = fmaxf(m[r], mt);
                float al = fexp2(m[r] - mn);
                m[r] = mn;
                ps[r] *= al;
                for (int nf = 0; nf < 4; nf++) o[nf][r] *= al;
            }
        }

        // native exp2 + P -> per-wave LDS (swizzled); no per-lane psum adds
        for (int kf = 0; kf < 4; kf++)
            for (int r = 0; r < 4; r++) {
                float p = fexp2(s[kf][r] - m[r]);
                int row = lg * 4 + r;
                int ch  = (kf * 2 + (lr >> 3)) ^ (row & 7);
                Ps[w][row * 64 + ch * 8 + sw] = f2bf_fast(p);
            }

        // O += P V (8 MFMA) and psum += P 1 (2 MFMA with ones-B)
        __builtin_amdgcn_s_setprio(1);
        for (int ks = 0; ks < 2; ks++) {
            bf16x8 pa = *(const bf16x8*)&Ps[w][lr * 64 + ((ks * 4 + lg) ^ sw) * 8];
            ps = __builtin_amdgcn_mfma_f32_16x16x32_bf16(pa, onesb, ps, 0, 0, 0);
            for (int nf = 0; nf < 4; nf++) {
                int d = nf * 16 + lr;
                bf16x8 bv = *(const bf16x8*)&Vl[d * 64 + ((ks * 4 + lg) ^ sw) * 8];
                o[nf] = __builtin_amdgcn_mfma_f32_16x16x32_bf16(pa, bv, o[nf], 0, 0, 0);
            }
        }
        __builtin_amdgcn_s_setprio(0);
        __syncthreads();
        bsel ^= 1;
    }

    // psum came out of the ones-MFMA (all d-columns equal) -- no reduce needed
    float rs[4];
    for (int r = 0; r < 4; r++) rs[r] = frcp(ps[r]);

    for (int nf = 0; nf < 4; nf++)
        for (int r = 0; r < 4; r++) {
            int row = qt * 128 + w * 16 + lg * 4 + r;
            int col = h * 64 + nf * 16 + lr;
            Out[((size_t)(b * T_ + row)) * E_ + col] = f2bf(o[nf][r] * rs[r]);
        }
}

// ---------------------------------------------------------------------------
extern "C" void kernel_launch(void* const* d_in, const int* in_sizes, int n_in,
                              void* d_out, int out_size, void* d_ws, size_t ws_size,
                              hipStream_t stream) {
    const float* v  = (const float*)d_in[0];
    const float* k  = (const float*)d_in[1];
    const float* q  = (const float*)d_in[2];
    const float* g  = (const float*)d_in[3];
    const float* be = (const float*)d_in[4];
    const float* Wq = (const float*)d_in[5];
    const float* Wk = (const float*)d_in[6];
    const float* Wv = (const float*)d_in[7];
    const float* Wp = (const float*)d_in[8];
    const float* bp = (const float*)d_in[9];
    float* out = (float*)d_out;

    // NOTE: no backslashes at end of comments (r11 compile failure).
    char* ws = (char*)d_ws;
    u16* qh  = (u16*)(ws);                // 8MB [B,H,T,64] (pre-scaled)
    u16* kh  = (u16*)(ws + (8u  << 20));  // 8MB [B,H,T,64]
    u16* vt  = (u16*)(ws + (16u << 20));  // 8MB [B,H,64,T]
    u16* qn  = (u16*)(ws + (24u << 20));  // 8MB [B,T,E] -- contiguous with kn,vn
    u16* kn  = (u16*)(ws + (32u << 20));  // 8MB
    u16* vn  = (u16*)(ws + (40u << 20));  // 8MB
    u16* wtq = (u16*)(ws + (48u << 20));  // 2MB each, contiguous stack
    u16* wtk = (u16*)(ws + (50u << 20));
    u16* wtv = (u16*)(ws + (52u << 20));
    u16* wtp = (u16*)(ws + (54u << 20));
    u16* ao  = (u16*)(ws + (24u << 20));  // alias qn (dead after projections)

    hipLaunchKernelGGL(wcast_t, dim3(32, 32, 4), dim3(256), 0, stream,
                       Wq, Wk, Wv, Wp, wtq, wtk, wtv, wtp);
    hipLaunchKernelGGL(ln_all, dim3(3 * BT_), dim3(256), 0, stream,
                       v, k, q, g, be, vn, kn, qn);
    hipLaunchKernelGGL(gemm8ph, dim3(4, 48), dim3(512), 0, stream,
                       qn, wtq, qh, kh, vt);
    hipLaunchKernelGGL(attn, dim3(8, 64), dim3(512), 0, stream,
                       qh, kh, vt, ao);
    hipLaunchKernelGGL(gemm128, dim3(8, 32), dim3(256), 0, stream,
                       ao, wtp, out, bp);
}